// Round 5
// baseline (816.388 us; speedup 1.0000x reference)
//
#include <hip/hip_runtime.h>
#include <stdint.h>

#define NN 8192
#define CC 128
#define BN_EPS 1e-5f
#define REG_CAP 512          // edges per (128-col x 256-row) region; mean 131, +33 sigma

typedef float vf4 __attribute__((ext_vector_type(4)));   // native vec: OK for nontemporal

__device__ inline unsigned short f2bf(float f) {
    unsigned int u = __float_as_uint(f);
    unsigned int r = (u + 0x7fffu + ((u >> 16) & 1u)) >> 16;   // RNE
    return (unsigned short)r;
}
__device__ inline float bf2f(unsigned short s) {
    return __uint_as_float(((unsigned int)s) << 16);
}

// ---------------------------------------------------------------------------
// Kernel 1a: pure A-stream scan. Grid (64 col-chunks, 32 row-slices) x 256.
// Wave w covers 64 rows x 128 cols; vf4 nontemporal loads (lanes 0-31 row j,
// 32-63 row j+1), ballot -> packed edge (j<<7 | local_col) appended to the
// region bucket; deg[j] += popcount. No X loads, no LDS tile -> high occupancy.
// Measured ~92 us (~2.9 TB/s A-stream) — unchanged this round.
// ---------------------------------------------------------------------------
__global__ __launch_bounds__(256) void k1_scan(
        const float* __restrict__ A, float* __restrict__ deg,
        unsigned* __restrict__ cnt, unsigned* __restrict__ edges) {
    const int tid  = threadIdx.x;
    const int lane = tid & 63;
    const int wave = tid >> 6;
    const int x = blockIdx.x, y = blockIdx.y;
    const int i0  = x * 128;
    const int reg = y * 64 + x;
    unsigned* eb = edges + (size_t)reg * REG_CAP;
    const int jb0 = y * 256 + wave * 64;
    const float* Ap = A + (size_t)(jb0 + (lane >> 5)) * NN + i0 + ((lane & 31) << 2);
    const unsigned long long lt = (1ull << lane) - 1ull;

    auto procb = [&](const vf4* a, int jb) {
        #pragma unroll
        for (int u = 0; u < 4; ++u) {
            vf4 v = a[u];
            int j0 = jb + 2 * u;
            unsigned long long m0 = __ballot(v.x != 0.0f);
            unsigned long long m1 = __ballot(v.y != 0.0f);
            unsigned long long m2 = __ballot(v.z != 0.0f);
            unsigned long long m3 = __ballot(v.w != 0.0f);
            if (!(m0 | m1 | m2 | m3)) continue;
            int cLo = __popc((unsigned)m0) + __popc((unsigned)m1)
                    + __popc((unsigned)m2) + __popc((unsigned)m3);
            int cHi = __popc((unsigned)(m0 >> 32)) + __popc((unsigned)(m1 >> 32))
                    + __popc((unsigned)(m2 >> 32)) + __popc((unsigned)(m3 >> 32));
            if (lane == 0 && cLo) atomicAdd(&deg[j0],     (float)cLo);
            if (lane == 1 && cHi) atomicAdd(&deg[j0 + 1], (float)cHi);
            unsigned base = 0;
            if (lane == 0) base = atomicAdd(&cnt[reg], (unsigned)(cLo + cHi));
            base = (unsigned)__shfl((int)base, 0);
            int j  = j0 + (lane >> 5);
            int cb = (lane & 31) << 2;
            unsigned long long mc[4] = {m0, m1, m2, m3};
            float vv[4] = {v.x, v.y, v.z, v.w};
            unsigned pre = base;
            #pragma unroll
            for (int c = 0; c < 4; ++c) {
                if (vv[c] != 0.0f) {
                    unsigned slot = pre + (unsigned)__popcll(mc[c] & lt);
                    if (slot < REG_CAP)
                        eb[slot] = ((unsigned)j << 7) | (unsigned)(cb + c);
                }
                pre += (unsigned)__popcll(mc[c]);
            }
        }
    };

#define LD(dst, roff) do { _Pragma("unroll")                                   \
    for (int u = 0; u < 4; ++u)                                                \
        dst[u] = __builtin_nontemporal_load(                                   \
            reinterpret_cast<const vf4*>(Ap + (size_t)((roff) + 2 * u) * NN)); \
    } while (0)

    vf4 a0[4], a1[4];
    LD(a0, 0);
    for (int nI = 0; nI < 4; ++nI) {           // 4 x 16 rows = 64 rows/wave
        int r = nI * 16;
        LD(a1, r + 8);
        procb(a0, jb0 + r);
        if (nI < 3) LD(a0, r + 16);
        procb(a1, jb0 + r + 8);
    }
#undef LD
}

// ---------------------------------------------------------------------------
// Kernel 1b: gather, atomic-free merge. Grid (64 col-chunks, 2 j-slices).
// Block (x,s) owns PRIVATE output slice aggS[s]+x*16384: waves accumulate
// their 4 regions (LDS atomics only), tile written once with plain stores.
// k2 sums the two slices. No global atomics, no aggU memset needed.
// ---------------------------------------------------------------------------
__global__ __launch_bounds__(256, 2) void k1b_gather(
        const float* __restrict__ X, const unsigned* __restrict__ cnt,
        const unsigned* __restrict__ edges, float* __restrict__ aggS) {
    __shared__ float acc[128 * 128];
    const int tid = threadIdx.x, lane = tid & 63, wave = tid >> 6;
    const int x = blockIdx.x, s = blockIdx.y;
    for (int t = tid; t < 128 * 128; t += 256) acc[t] = 0.0f;
    __syncthreads();

#define LE(e_, t0_) do { _Pragma("unroll")                                     \
    for (int u = 0; u < 4; ++u) e_[u] = eb[(t0_) + u]; } while (0)
#define LX(e_, xa_, xb_) do { _Pragma("unroll")                                \
    for (int u = 0; u < 4; ++u) { int j_ = (int)(e_[u] >> 7);                  \
        xa_[u] = X[j_ * CC + lane]; xb_[u] = X[j_ * CC + 64 + lane]; } } while (0)
#define PR(e_, xa_, xb_) do { _Pragma("unroll")                                \
    for (int u = 0; u < 4; ++u) { int il_ = (int)(e_[u] & 127u);               \
        atomicAdd(&acc[il_ * 128 + lane],      xa_[u]);                        \
        atomicAdd(&acc[il_ * 128 + 64 + lane], xb_[u]); } } while (0)

    for (int rr = 0; rr < 4; ++rr) {          // 4 regions per wave
        const int reg = (s * 16 + wave * 4 + rr) * 64 + x;
        const unsigned* eb = edges + (size_t)reg * REG_CAP;
        unsigned n = cnt[reg]; if (n > REG_CAP) n = REG_CAP;

        unsigned e0[4], e1[4];
        float xa0[4], xb0[4], xa1[4], xb1[4];
        unsigned base = 0;
        if (n >= 8) {
            LE(e0, 0); LX(e0, xa0, xb0);
            while (base + 8 <= n) {
                LE(e1, base + 4); LX(e1, xa1, xb1);
                PR(e0, xa0, xb0);
                if (base + 12 <= n) { LE(e0, base + 8); LX(e0, xa0, xb0); }
                PR(e1, xa1, xb1);
                base += 8;
            }
        }
        for (unsigned t = base; t < n; ++t) {
            unsigned e = eb[t]; int j = (int)(e >> 7), il = (int)(e & 127u);
            atomicAdd(&acc[il * 128 + lane],      X[j * CC + lane]);
            atomicAdd(&acc[il * 128 + 64 + lane], X[j * CC + 64 + lane]);
        }
    }
#undef LE
#undef LX
#undef PR
    __syncthreads();
    float* out = aggS + (size_t)s * (NN / 2) * CC * 2   // slice s base (4 MB apart)
               + (size_t)x * 128 * CC;
    for (int t = tid; t < 128 * 128; t += 256) out[t] = acc[t];
}

// ---------------------------------------------------------------------------
// Kernel 2: h = ((s0+s1)/deg) @ Wn^T + X @ Wc^T + bn + bc, fused BN sums.
// ---------------------------------------------------------------------------
__global__ __launch_bounds__(256, 2) void k2_gemm(
        const float* __restrict__ aggS0, const float* __restrict__ aggS1,
        const float* __restrict__ deg, const float* __restrict__ X,
        const float* __restrict__ Wn, const float* __restrict__ bn,
        const float* __restrict__ Wc, const float* __restrict__ bc,
        float* __restrict__ h, float* __restrict__ bsum, float* __restrict__ bsq) {
    __shared__ unsigned short WtN[128 * 128];   // WtN[k*128+c] = bf16(Wn[c,k])
    __shared__ unsigned short WtC[128 * 128];
    const int tid = threadIdx.x;
    for (int idx = tid * 4; idx < 128 * 128; idx += 1024) {
        float4 wn4 = *reinterpret_cast<const float4*>(Wn + idx);
        float4 wc4 = *reinterpret_cast<const float4*>(Wc + idx);
        int c = idx >> 7, k0 = idx & 127;       // 4 consecutive k, same c
        WtN[(k0 + 0) * 128 + c] = f2bf(wn4.x);
        WtN[(k0 + 1) * 128 + c] = f2bf(wn4.y);
        WtN[(k0 + 2) * 128 + c] = f2bf(wn4.z);
        WtN[(k0 + 3) * 128 + c] = f2bf(wn4.w);
        WtC[(k0 + 0) * 128 + c] = f2bf(wc4.x);
        WtC[(k0 + 1) * 128 + c] = f2bf(wc4.y);
        WtC[(k0 + 2) * 128 + c] = f2bf(wc4.z);
        WtC[(k0 + 3) * 128 + c] = f2bf(wc4.w);
    }
    __syncthreads();
    const int c  = tid & 127;
    const int rg = tid >> 7;
    const int i0 = blockIdx.x * 16 + rg * 8;

    float accN[8], accC[8];
    #pragma unroll
    for (int r = 0; r < 8; ++r) { accN[r] = 0.0f; accC[r] = 0.0f; }

    float4 ar[8], xr[8], an[8], xn[8];

#define LOADK(ab_, xb_, k_) do {                                               \
    _Pragma("unroll")                                                          \
    for (int r = 0; r < 8; ++r) {                                              \
        size_t off_ = (size_t)(i0 + r) * CC + (k_);                            \
        float4 p_ = *reinterpret_cast<const float4*>(aggS0 + off_);            \
        float4 q_ = *reinterpret_cast<const float4*>(aggS1 + off_);            \
        ab_[r].x = p_.x + q_.x; ab_[r].y = p_.y + q_.y;                        \
        ab_[r].z = p_.z + q_.z; ab_[r].w = p_.w + q_.w;                        \
        xb_[r] = *reinterpret_cast<const float4*>(&X[off_]);                   \
    }                                                                          \
} while (0)

#define COMPK(ab_, xb_, k_) do {                                               \
    _Pragma("unroll")                                                          \
    for (int kk = 0; kk < 4; ++kk) {                                           \
        float wn_ = bf2f(WtN[((k_) + kk) * 128 + c]);                          \
        float wc_ = bf2f(WtC[((k_) + kk) * 128 + c]);                          \
        _Pragma("unroll")                                                      \
        for (int r = 0; r < 8; ++r) {                                          \
            accN[r] = fmaf((&ab_[r].x)[kk], wn_, accN[r]);                     \
            accC[r] = fmaf((&xb_[r].x)[kk], wc_, accC[r]);                     \
        }                                                                      \
    }                                                                          \
} while (0)

    LOADK(ar, xr, 0);
    for (int k = 0; k < 128; k += 8) {
        LOADK(an, xn, k + 4);
        COMPK(ar, xr, k);
        if (k + 8 < 128) LOADK(ar, xr, k + 8);
        COMPK(an, xn, k + 4);
    }
#undef LOADK
#undef COMPK

    const float bnc = bn[c], bcc = bc[c];
    float sp = 0.0f, sq = 0.0f;
    #pragma unroll
    for (int r = 0; r < 8; ++r) {
        float d  = deg[i0 + r];
        float rd = (d == 0.0f) ? 1.0f : (1.0f / d);
        float hv = accN[r] * rd + accC[r] + bnc + bcc;
        h[(size_t)(i0 + r) * CC + c] = hv;
        sp += hv; sq += hv * hv;
    }
    __syncthreads();                              // WtN reads done; reuse as fp32 scratch
    float* red = reinterpret_cast<float*>(WtN);
    red[rg * 128 + c]       = sp;
    red[256 + rg * 128 + c] = sq;
    __syncthreads();
    if (rg == 0) {
        atomicAdd(&bsum[c], red[c] + red[128 + c]);
        atomicAdd(&bsq[c],  red[256 + c] + red[384 + c]);
    }
}

// ---------------------------------------------------------------------------
// Kernel 3: out = relu(gamma * (h - mu) * rsqrt(var + eps) + beta), float4.
// ---------------------------------------------------------------------------
__global__ __launch_bounds__(256) void k4_bn(
        const float* __restrict__ h, const float* __restrict__ bsum,
        const float* __restrict__ bsq, const float* __restrict__ gamma,
        const float* __restrict__ beta, float* __restrict__ out) {
    const int idx = (blockIdx.x * 256 + threadIdx.x) * 4;
    const int c0  = idx & 127;
    float4 hv = *reinterpret_cast<const float4*>(h + idx);
    float4 s4 = *reinterpret_cast<const float4*>(bsum + c0);
    float4 q4 = *reinterpret_cast<const float4*>(bsq + c0);
    float4 g4 = *reinterpret_cast<const float4*>(gamma + c0);
    float4 b4 = *reinterpret_cast<const float4*>(beta + c0);
    const float invN = 1.0f / 8192.0f;
    float4 o;
    const float* hp = &hv.x; const float* sp = &s4.x; const float* qp = &q4.x;
    const float* gp = &g4.x; const float* bp = &b4.x; float* op = &o.x;
    #pragma unroll
    for (int jj = 0; jj < 4; ++jj) {
        float mu  = sp[jj] * invN;
        float var = qp[jj] * invN - mu * mu;
        float sc  = gp[jj] * rsqrtf(var + BN_EPS);
        float v   = (hp[jj] - mu) * sc + bp[jj];
        op[jj] = v > 0.0f ? v : 0.0f;
    }
    *reinterpret_cast<float4*>(out + idx) = o;
}

extern "C" void kernel_launch(void* const* d_in, const int* in_sizes, int n_in,
                              void* d_out, int out_size, void* d_ws, size_t ws_size,
                              hipStream_t stream) {
    const float* X     = (const float*)d_in[0];   // [8192,128]
    const float* A     = (const float*)d_in[1];   // [8192,8192]
    const float* Wn    = (const float*)d_in[2];   // [128,128]
    const float* bn    = (const float*)d_in[3];
    const float* Wc    = (const float*)d_in[4];
    const float* bc    = (const float*)d_in[5];
    const float* gamma = (const float*)d_in[6];
    const float* beta  = (const float*)d_in[7];
    float* out = (float*)d_out;

    char* ws = (char*)d_ws;
    float*    aggS  = (float*)(ws);                   // 2 x 4 MB slices (plain stores)
    float*    aggS1 = (float*)(ws + 4194304);
    float*    deg   = (float*)(ws + 8388608);         // 32 KB  (memset 0)
    float*    bsum  = (float*)(ws + 8421376);         // 512 B  (memset 0)
    float*    bsq   = (float*)(ws + 8421888);         // 512 B  (memset 0)
    unsigned* cnt   = (unsigned*)(ws + 8422400);      // 8 KB   (memset 0)
    float*    h     = (float*)(ws + 8430592);         // 4 MB
    unsigned* edges = (unsigned*)(ws + 8430592);      // aliases h (dead before k2)

    // only the small accumulated regions need zeroing now (42 KB)
    hipMemsetAsync(ws + 8388608, 0, 41984, stream);

    k1_scan   <<<dim3(64, 32), 256, 0, stream>>>(A, deg, cnt, edges);
    k1b_gather<<<dim3(64, 2),  256, 0, stream>>>(X, cnt, edges, aggS);
    k2_gemm   <<<512, 256, 0, stream>>>(aggS, aggS1, deg, X, Wn, bn, Wc, bc,
                                        h, bsum, bsq);
    k4_bn     <<<1024, 256, 0, stream>>>(h, bsum, bsq, gamma, beta, out);
}

// Round 6
// 809.462 us; speedup vs baseline: 1.0086x; 1.0086x over previous
//
#include <hip/hip_runtime.h>
#include <stdint.h>

#define NN 8192
#define CC 128
#define BN_EPS 1e-5f
#define REG_CAP 512          // edges per (128-col x 256-row) region; mean 131

typedef float vf4 __attribute__((ext_vector_type(4)));   // native vec: OK for nontemporal

__device__ inline unsigned short f2bf(float f) {
    unsigned int u = __float_as_uint(f);
    unsigned int r = (u + 0x7fffu + ((u >> 16) & 1u)) >> 16;   // RNE
    return (unsigned short)r;
}
__device__ inline float bf2f(unsigned short s) {
    return __uint_as_float(((unsigned int)s) << 16);
}

// ---------------------------------------------------------------------------
// Kernel 1a: pure A-stream scan (unchanged; ~92 us, ~2.9 TB/s).
// ---------------------------------------------------------------------------
__global__ __launch_bounds__(256) void k1_scan(
        const float* __restrict__ A, float* __restrict__ deg,
        unsigned* __restrict__ cnt, unsigned* __restrict__ edges) {
    const int tid  = threadIdx.x;
    const int lane = tid & 63;
    const int wave = tid >> 6;
    const int x = blockIdx.x, y = blockIdx.y;
    const int i0  = x * 128;
    const int reg = y * 64 + x;
    unsigned* eb = edges + (size_t)reg * REG_CAP;
    const int jb0 = y * 256 + wave * 64;
    const float* Ap = A + (size_t)(jb0 + (lane >> 5)) * NN + i0 + ((lane & 31) << 2);
    const unsigned long long lt = (1ull << lane) - 1ull;

    auto procb = [&](const vf4* a, int jb) {
        #pragma unroll
        for (int u = 0; u < 4; ++u) {
            vf4 v = a[u];
            int j0 = jb + 2 * u;
            unsigned long long m0 = __ballot(v.x != 0.0f);
            unsigned long long m1 = __ballot(v.y != 0.0f);
            unsigned long long m2 = __ballot(v.z != 0.0f);
            unsigned long long m3 = __ballot(v.w != 0.0f);
            if (!(m0 | m1 | m2 | m3)) continue;
            int cLo = __popc((unsigned)m0) + __popc((unsigned)m1)
                    + __popc((unsigned)m2) + __popc((unsigned)m3);
            int cHi = __popc((unsigned)(m0 >> 32)) + __popc((unsigned)(m1 >> 32))
                    + __popc((unsigned)(m2 >> 32)) + __popc((unsigned)(m3 >> 32));
            if (lane == 0 && cLo) atomicAdd(&deg[j0],     (float)cLo);
            if (lane == 1 && cHi) atomicAdd(&deg[j0 + 1], (float)cHi);
            unsigned base = 0;
            if (lane == 0) base = atomicAdd(&cnt[reg], (unsigned)(cLo + cHi));
            base = (unsigned)__shfl((int)base, 0);
            int j  = j0 + (lane >> 5);
            int cb = (lane & 31) << 2;
            unsigned long long mc[4] = {m0, m1, m2, m3};
            float vv[4] = {v.x, v.y, v.z, v.w};
            unsigned pre = base;
            #pragma unroll
            for (int c = 0; c < 4; ++c) {
                if (vv[c] != 0.0f) {
                    unsigned slot = pre + (unsigned)__popcll(mc[c] & lt);
                    if (slot < REG_CAP)
                        eb[slot] = ((unsigned)j << 7) | (unsigned)(cb + c);
                }
                pre += (unsigned)__popcll(mc[c]);
            }
        }
    };

#define LD(dst, roff) do { _Pragma("unroll")                                   \
    for (int u = 0; u < 4; ++u)                                                \
        dst[u] = __builtin_nontemporal_load(                                   \
            reinterpret_cast<const vf4*>(Ap + (size_t)((roff) + 2 * u) * NN)); \
    } while (0)

    vf4 a0[4], a1[4];
    LD(a0, 0);
    for (int nI = 0; nI < 4; ++nI) {           // 4 x 16 rows = 64 rows/wave
        int r = nI * 16;
        LD(a1, r + 8);
        procb(a0, jb0 + r);
        if (nI < 3) LD(a0, r + 16);
        procb(a1, jb0 + r + 8);
    }
#undef LD
}

// ---------------------------------------------------------------------------
// Kernel 1b: gather with full TLP + 3-stage pipeline, atomic-free merge.
// Grid (64 x-chunks, S slices) x BS thr; one 256-row region per wave.
// Chunk = 8 edges (2 x uint4 loads). Iter k: issue X(k+1) from edges loaded
// an iteration ago; prefetch edges(k+2); process chunk k (X data has a full
// iteration of slack). LDS fp32 tile, one plain-store write to private slice.
// ---------------------------------------------------------------------------
template<int BS>
__global__ __launch_bounds__(BS) void k1b_gather(
        const float* __restrict__ X, const unsigned* __restrict__ cnt,
        const unsigned* __restrict__ edges, float* __restrict__ aggS) {
    __shared__ float acc[128 * 128];
    const int tid = threadIdx.x, lane = tid & 63, wave = tid >> 6;
    constexpr int WPB = BS / 64;
    const int x = blockIdx.x, s = blockIdx.y;
    for (int t = tid; t < 128 * 128; t += BS) acc[t] = 0.0f;
    __syncthreads();
    const int reg = (s * WPB + wave) * 64 + x;
    const unsigned* eb = edges + (size_t)reg * REG_CAP;
    unsigned n = cnt[reg]; if (n > REG_CAP) n = REG_CAP;
    const unsigned nch = n >> 3;

    uint4 EA0, EB0, EA1, EB1;
    float xa0[8], xb0[8], xa1[8], xb1[8];
    unsigned il0[8], il1[8];

#define LOADE(k_, EA_, EB_) do {                                               \
    const uint4* p_ = reinterpret_cast<const uint4*>(eb + (k_) * 8);           \
    EA_ = p_[0]; EB_ = p_[1]; } while (0)

#define ISSUEX(EA_, EB_, xa_, xb_, il_) do {                                   \
    unsigned e_[8] = {EA_.x, EA_.y, EA_.z, EA_.w, EB_.x, EB_.y, EB_.z, EB_.w}; \
    _Pragma("unroll")                                                          \
    for (int u = 0; u < 8; ++u) {                                              \
        int j_ = (int)(e_[u] >> 7);                                            \
        il_[u] = e_[u] & 127u;                                                 \
        xa_[u] = X[j_ * CC + lane];                                            \
        xb_[u] = X[j_ * CC + 64 + lane];                                       \
    } } while (0)

#define PROC(xa_, xb_, il_) do { _Pragma("unroll")                             \
    for (int u = 0; u < 8; ++u) {                                              \
        int r_ = (int)il_[u] * 128;                                            \
        atomicAdd(&acc[r_ + lane],      xa_[u]);                               \
        atomicAdd(&acc[r_ + 64 + lane], xb_[u]);                               \
    } } while (0)

    if (nch >= 1) {
        LOADE(0, EA0, EB0);
        if (nch >= 2) LOADE(1, EA1, EB1);
        ISSUEX(EA0, EB0, xa0, xb0, il0);          // chunk 0 X in flight
        for (unsigned k = 0; k < nch; ++k) {
            if ((k & 1) == 0) {
                if (k + 1 < nch) ISSUEX(EA1, EB1, xa1, xb1, il1);
                if (k + 2 < nch) LOADE(k + 2, EA0, EB0);
                PROC(xa0, xb0, il0);
            } else {
                if (k + 1 < nch) ISSUEX(EA0, EB0, xa0, xb0, il0);
                if (k + 2 < nch) LOADE(k + 2, EA1, EB1);
                PROC(xa1, xb1, il1);
            }
        }
    }
    for (unsigned t = nch * 8; t < n; ++t) {      // tail (<8 edges)
        unsigned e = eb[t]; int j = (int)(e >> 7), il = (int)(e & 127u);
        atomicAdd(&acc[il * 128 + lane],      X[j * CC + lane]);
        atomicAdd(&acc[il * 128 + 64 + lane], X[j * CC + 64 + lane]);
    }
#undef LOADE
#undef ISSUEX
#undef PROC
    __syncthreads();
    float* out = aggS + (size_t)s * (NN * CC) + (size_t)x * 128 * CC;
    for (int t = tid; t < 128 * 128; t += BS) out[t] = acc[t];
}

// ---------------------------------------------------------------------------
// Kernel 2: h = (sum_s slice_s / deg) @ Wn^T + X @ Wc^T + b, fused BN sums.
// ---------------------------------------------------------------------------
template<int S>
__global__ __launch_bounds__(256, 2) void k2_gemm(
        const float* __restrict__ aggS, const float* __restrict__ deg,
        const float* __restrict__ X,
        const float* __restrict__ Wn, const float* __restrict__ bn,
        const float* __restrict__ Wc, const float* __restrict__ bc,
        float* __restrict__ h, float* __restrict__ bsum, float* __restrict__ bsq) {
    __shared__ unsigned short WtN[128 * 128];   // WtN[k*128+c] = bf16(Wn[c,k])
    __shared__ unsigned short WtC[128 * 128];
    const int tid = threadIdx.x;
    for (int idx = tid * 4; idx < 128 * 128; idx += 1024) {
        float4 wn4 = *reinterpret_cast<const float4*>(Wn + idx);
        float4 wc4 = *reinterpret_cast<const float4*>(Wc + idx);
        int c = idx >> 7, k0 = idx & 127;
        WtN[(k0 + 0) * 128 + c] = f2bf(wn4.x);
        WtN[(k0 + 1) * 128 + c] = f2bf(wn4.y);
        WtN[(k0 + 2) * 128 + c] = f2bf(wn4.z);
        WtN[(k0 + 3) * 128 + c] = f2bf(wn4.w);
        WtC[(k0 + 0) * 128 + c] = f2bf(wc4.x);
        WtC[(k0 + 1) * 128 + c] = f2bf(wc4.y);
        WtC[(k0 + 2) * 128 + c] = f2bf(wc4.z);
        WtC[(k0 + 3) * 128 + c] = f2bf(wc4.w);
    }
    __syncthreads();
    const int c  = tid & 127;
    const int rg = tid >> 7;
    const int i0 = blockIdx.x * 16 + rg * 8;

    float accN[8], accC[8];
    #pragma unroll
    for (int r = 0; r < 8; ++r) { accN[r] = 0.0f; accC[r] = 0.0f; }

    float4 ar[8], xr[8], an[8], xn[8];

#define LOADK(ab_, xb_, k_) do {                                               \
    _Pragma("unroll")                                                          \
    for (int r = 0; r < 8; ++r) {                                              \
        size_t off_ = (size_t)(i0 + r) * CC + (k_);                            \
        float4 p_ = *reinterpret_cast<const float4*>(aggS + off_);             \
        _Pragma("unroll")                                                      \
        for (int ss = 1; ss < S; ++ss) {                                       \
            float4 q_ = *reinterpret_cast<const float4*>(                      \
                aggS + (size_t)ss * (NN * CC) + off_);                         \
            p_.x += q_.x; p_.y += q_.y; p_.z += q_.z; p_.w += q_.w;            \
        }                                                                      \
        ab_[r] = p_;                                                           \
        xb_[r] = *reinterpret_cast<const float4*>(&X[off_]);                   \
    }                                                                          \
} while (0)

#define COMPK(ab_, xb_, k_) do {                                               \
    _Pragma("unroll")                                                          \
    for (int kk = 0; kk < 4; ++kk) {                                           \
        float wn_ = bf2f(WtN[((k_) + kk) * 128 + c]);                          \
        float wc_ = bf2f(WtC[((k_) + kk) * 128 + c]);                          \
        _Pragma("unroll")                                                      \
        for (int r = 0; r < 8; ++r) {                                          \
            accN[r] = fmaf((&ab_[r].x)[kk], wn_, accN[r]);                     \
            accC[r] = fmaf((&xb_[r].x)[kk], wc_, accC[r]);                     \
        }                                                                      \
    }                                                                          \
} while (0)

    LOADK(ar, xr, 0);
    for (int k = 0; k < 128; k += 8) {
        LOADK(an, xn, k + 4);
        COMPK(ar, xr, k);
        if (k + 8 < 128) LOADK(ar, xr, k + 8);
        COMPK(an, xn, k + 4);
    }
#undef LOADK
#undef COMPK

    const float bnc = bn[c], bcc = bc[c];
    float sp = 0.0f, sq = 0.0f;
    #pragma unroll
    for (int r = 0; r < 8; ++r) {
        float d  = deg[i0 + r];
        float rd = (d == 0.0f) ? 1.0f : (1.0f / d);
        float hv = accN[r] * rd + accC[r] + bnc + bcc;
        h[(size_t)(i0 + r) * CC + c] = hv;
        sp += hv; sq += hv * hv;
    }
    __syncthreads();                              // WtN reads done; reuse as scratch
    float* red = reinterpret_cast<float*>(WtN);
    red[rg * 128 + c]       = sp;
    red[256 + rg * 128 + c] = sq;
    __syncthreads();
    if (rg == 0) {
        atomicAdd(&bsum[c], red[c] + red[128 + c]);
        atomicAdd(&bsq[c],  red[256 + c] + red[384 + c]);
    }
}

// ---------------------------------------------------------------------------
// Kernel 3: out = relu(gamma * (h - mu) * rsqrt(var + eps) + beta), float4.
// ---------------------------------------------------------------------------
__global__ __launch_bounds__(256) void k4_bn(
        const float* __restrict__ h, const float* __restrict__ bsum,
        const float* __restrict__ bsq, const float* __restrict__ gamma,
        const float* __restrict__ beta, float* __restrict__ out) {
    const int idx = (blockIdx.x * 256 + threadIdx.x) * 4;
    const int c0  = idx & 127;
    float4 hv = *reinterpret_cast<const float4*>(h + idx);
    float4 s4 = *reinterpret_cast<const float4*>(bsum + c0);
    float4 q4 = *reinterpret_cast<const float4*>(bsq + c0);
    float4 g4 = *reinterpret_cast<const float4*>(gamma + c0);
    float4 b4 = *reinterpret_cast<const float4*>(beta + c0);
    const float invN = 1.0f / 8192.0f;
    float4 o;
    const float* hp = &hv.x; const float* sp = &s4.x; const float* qp = &q4.x;
    const float* gp = &g4.x; const float* bp = &b4.x; float* op = &o.x;
    #pragma unroll
    for (int jj = 0; jj < 4; ++jj) {
        float mu  = sp[jj] * invN;
        float var = qp[jj] * invN - mu * mu;
        float sc  = gp[jj] * rsqrtf(var + BN_EPS);
        float v   = (hp[jj] - mu) * sc + bp[jj];
        op[jj] = v > 0.0f ? v : 0.0f;
    }
    *reinterpret_cast<float4*>(out + idx) = o;
}

extern "C" void kernel_launch(void* const* d_in, const int* in_sizes, int n_in,
                              void* d_out, int out_size, void* d_ws, size_t ws_size,
                              hipStream_t stream) {
    const float* X     = (const float*)d_in[0];   // [8192,128]
    const float* A     = (const float*)d_in[1];   // [8192,8192]
    const float* Wn    = (const float*)d_in[2];   // [128,128]
    const float* bn    = (const float*)d_in[3];
    const float* Wc    = (const float*)d_in[4];
    const float* bc    = (const float*)d_in[5];
    const float* gamma = (const float*)d_in[6];
    const float* beta  = (const float*)d_in[7];
    float* out = (float*)d_out;

    const size_t sliceB = 4194304;                // 4 MB per slice
    const size_t smallB = 41984;                  // deg+bsum+bsq+cnt
    // 4 slices needs ~21 MB of ws; fall back to 2 slices (1024-thr blocks) if tight.
    const int S = (ws_size >= 4 * sliceB + smallB + sliceB) ? 4 : 2;

    char* ws = (char*)d_ws;
    float*    aggS  = (float*)(ws);                       // S x 4 MB, plain stores
    char*     smal  = ws + (size_t)S * sliceB;
    float*    deg   = (float*)(smal);                     // 32 KB  (memset 0)
    float*    bsum  = (float*)(smal + 32768);             // 512 B  (memset 0)
    float*    bsq   = (float*)(smal + 33280);             // 512 B  (memset 0)
    unsigned* cnt   = (unsigned*)(smal + 33792);          // 8 KB   (memset 0)
    float*    h     = (float*)(smal + smallB);            // 4 MB
    unsigned* edges = (unsigned*)(smal + smallB);         // aliases h (dead before k2)

    hipMemsetAsync(smal, 0, smallB, stream);

    k1_scan<<<dim3(64, 32), 256, 0, stream>>>(A, deg, cnt, edges);
    if (S == 4)
        k1b_gather<512><<<dim3(64, 4), 512, 0, stream>>>(X, cnt, edges, aggS);
    else
        k1b_gather<1024><<<dim3(64, 2), 1024, 0, stream>>>(X, cnt, edges, aggS);
    if (S == 4)
        k2_gemm<4><<<512, 256, 0, stream>>>(aggS, deg, X, Wn, bn, Wc, bc,
                                            h, bsum, bsq);
    else
        k2_gemm<2><<<512, 256, 0, stream>>>(aggS, deg, X, Wn, bn, Wc, bc,
                                            h, bsum, bsq);
    k4_bn<<<1024, 256, 0, stream>>>(h, bsum, bsq, gamma, beta, out);
}

// Round 7
// 579.816 us; speedup vs baseline: 1.4080x; 1.3961x over previous
//
#include <hip/hip_runtime.h>
#include <stdint.h>

#define NN 8192
#define CC 128
#define BN_EPS 1e-5f
#define REG_CAP 512          // edges per (128-col x 256-row) region; mean 131

typedef float vf4 __attribute__((ext_vector_type(4)));   // native vec: OK for nontemporal

__device__ inline unsigned short f2bf(float f) {
    unsigned int u = __float_as_uint(f);
    unsigned int r = (u + 0x7fffu + ((u >> 16) & 1u)) >> 16;   // RNE
    return (unsigned short)r;
}
__device__ inline float bf2f(unsigned short s) {
    return __uint_as_float(((unsigned int)s) << 16);
}

// ---------------------------------------------------------------------------
// Kernel 0: one-time W transpose to bf16 [k][c] layout in ws.
// Grid 32 x 256. Reads are 512B-stride scattered (L2-hot, 64 KB total);
// writes coalesced ushort. ~1-2 us.
// ---------------------------------------------------------------------------
__global__ __launch_bounds__(256) void k0_prep(
        const float* __restrict__ Wn, const float* __restrict__ Wc,
        unsigned short* __restrict__ WtNg, unsigned short* __restrict__ WtCg) {
    int idx = blockIdx.x * 512 + threadIdx.x;
    #pragma unroll
    for (int rep = 0; rep < 2; ++rep, idx += 256) {
        int k = idx >> 7, c = idx & 127;
        WtNg[idx] = f2bf(Wn[c * 128 + k]);
        WtCg[idx] = f2bf(Wc[c * 128 + k]);
    }
}

// ---------------------------------------------------------------------------
// Kernel 1a: pure A-stream scan (unchanged; ~92 us, ~2.9 TB/s).
// ---------------------------------------------------------------------------
__global__ __launch_bounds__(256) void k1_scan(
        const float* __restrict__ A, float* __restrict__ deg,
        unsigned* __restrict__ cnt, unsigned* __restrict__ edges) {
    const int tid  = threadIdx.x;
    const int lane = tid & 63;
    const int wave = tid >> 6;
    const int x = blockIdx.x, y = blockIdx.y;
    const int i0  = x * 128;
    const int reg = y * 64 + x;
    unsigned* eb = edges + (size_t)reg * REG_CAP;
    const int jb0 = y * 256 + wave * 64;
    const float* Ap = A + (size_t)(jb0 + (lane >> 5)) * NN + i0 + ((lane & 31) << 2);
    const unsigned long long lt = (1ull << lane) - 1ull;

    auto procb = [&](const vf4* a, int jb) {
        #pragma unroll
        for (int u = 0; u < 4; ++u) {
            vf4 v = a[u];
            int j0 = jb + 2 * u;
            unsigned long long m0 = __ballot(v.x != 0.0f);
            unsigned long long m1 = __ballot(v.y != 0.0f);
            unsigned long long m2 = __ballot(v.z != 0.0f);
            unsigned long long m3 = __ballot(v.w != 0.0f);
            if (!(m0 | m1 | m2 | m3)) continue;
            int cLo = __popc((unsigned)m0) + __popc((unsigned)m1)
                    + __popc((unsigned)m2) + __popc((unsigned)m3);
            int cHi = __popc((unsigned)(m0 >> 32)) + __popc((unsigned)(m1 >> 32))
                    + __popc((unsigned)(m2 >> 32)) + __popc((unsigned)(m3 >> 32));
            if (lane == 0 && cLo) atomicAdd(&deg[j0],     (float)cLo);
            if (lane == 1 && cHi) atomicAdd(&deg[j0 + 1], (float)cHi);
            unsigned base = 0;
            if (lane == 0) base = atomicAdd(&cnt[reg], (unsigned)(cLo + cHi));
            base = (unsigned)__shfl((int)base, 0);
            int j  = j0 + (lane >> 5);
            int cb = (lane & 31) << 2;
            unsigned long long mc[4] = {m0, m1, m2, m3};
            float vv[4] = {v.x, v.y, v.z, v.w};
            unsigned pre = base;
            #pragma unroll
            for (int c = 0; c < 4; ++c) {
                if (vv[c] != 0.0f) {
                    unsigned slot = pre + (unsigned)__popcll(mc[c] & lt);
                    if (slot < REG_CAP)
                        eb[slot] = ((unsigned)j << 7) | (unsigned)(cb + c);
                }
                pre += (unsigned)__popcll(mc[c]);
            }
        }
    };

#define LD(dst, roff) do { _Pragma("unroll")                                   \
    for (int u = 0; u < 4; ++u)                                                \
        dst[u] = __builtin_nontemporal_load(                                   \
            reinterpret_cast<const vf4*>(Ap + (size_t)((roff) + 2 * u) * NN)); \
    } while (0)

    vf4 a0[4], a1[4];
    LD(a0, 0);
    for (int nI = 0; nI < 4; ++nI) {           // 4 x 16 rows = 64 rows/wave
        int r = nI * 16;
        LD(a1, r + 8);
        procb(a0, jb0 + r);
        if (nI < 3) LD(a0, r + 16);
        procb(a1, jb0 + r + 8);
    }
#undef LD
}

// ---------------------------------------------------------------------------
// Kernel 1b: gather (unchanged from R6): full TLP, 3-stage pipeline,
// atomic-free merge into private slice. One 256-row region per wave.
// ---------------------------------------------------------------------------
template<int BS>
__global__ __launch_bounds__(BS) void k1b_gather(
        const float* __restrict__ X, const unsigned* __restrict__ cnt,
        const unsigned* __restrict__ edges, float* __restrict__ aggS) {
    __shared__ float acc[128 * 128];
    const int tid = threadIdx.x, lane = tid & 63, wave = tid >> 6;
    constexpr int WPB = BS / 64;
    const int x = blockIdx.x, s = blockIdx.y;
    for (int t = tid; t < 128 * 128; t += BS) acc[t] = 0.0f;
    __syncthreads();
    const int reg = (s * WPB + wave) * 64 + x;
    const unsigned* eb = edges + (size_t)reg * REG_CAP;
    unsigned n = cnt[reg]; if (n > REG_CAP) n = REG_CAP;
    const unsigned nch = n >> 3;

    uint4 EA0, EB0, EA1, EB1;
    float xa0[8], xb0[8], xa1[8], xb1[8];
    unsigned il0[8], il1[8];

#define LOADE(k_, EA_, EB_) do {                                               \
    const uint4* p_ = reinterpret_cast<const uint4*>(eb + (k_) * 8);           \
    EA_ = p_[0]; EB_ = p_[1]; } while (0)

#define ISSUEX(EA_, EB_, xa_, xb_, il_) do {                                   \
    unsigned e_[8] = {EA_.x, EA_.y, EA_.z, EA_.w, EB_.x, EB_.y, EB_.z, EB_.w}; \
    _Pragma("unroll")                                                          \
    for (int u = 0; u < 8; ++u) {                                              \
        int j_ = (int)(e_[u] >> 7);                                            \
        il_[u] = e_[u] & 127u;                                                 \
        xa_[u] = X[j_ * CC + lane];                                            \
        xb_[u] = X[j_ * CC + 64 + lane];                                       \
    } } while (0)

#define PROC(xa_, xb_, il_) do { _Pragma("unroll")                             \
    for (int u = 0; u < 8; ++u) {                                              \
        int r_ = (int)il_[u] * 128;                                            \
        atomicAdd(&acc[r_ + lane],      xa_[u]);                               \
        atomicAdd(&acc[r_ + 64 + lane], xb_[u]);                               \
    } } while (0)

    if (nch >= 1) {
        LOADE(0, EA0, EB0);
        if (nch >= 2) LOADE(1, EA1, EB1);
        ISSUEX(EA0, EB0, xa0, xb0, il0);
        for (unsigned k = 0; k < nch; ++k) {
            if ((k & 1) == 0) {
                if (k + 1 < nch) ISSUEX(EA1, EB1, xa1, xb1, il1);
                if (k + 2 < nch) LOADE(k + 2, EA0, EB0);
                PROC(xa0, xb0, il0);
            } else {
                if (k + 1 < nch) ISSUEX(EA0, EB0, xa0, xb0, il0);
                if (k + 2 < nch) LOADE(k + 2, EA1, EB1);
                PROC(xa1, xb1, il1);
            }
        }
    }
    for (unsigned t = nch * 8; t < n; ++t) {
        unsigned e = eb[t]; int j = (int)(e >> 7), il = (int)(e & 127u);
        atomicAdd(&acc[il * 128 + lane],      X[j * CC + lane]);
        atomicAdd(&acc[il * 128 + 64 + lane], X[j * CC + 64 + lane]);
    }
#undef LOADE
#undef ISSUEX
#undef PROC
    __syncthreads();
    float* outp = aggS + (size_t)s * (NN * CC) + (size_t)x * 128 * CC;
    for (int t = tid; t < 128 * 128; t += BS) outp[t] = acc[t];
}

// ---------------------------------------------------------------------------
// Kernel 2 (REWRITTEN): h = (sum_s slice_s / deg) @ Wn^T + X @ Wc^T + b,
// fused BN partials. Block = 32 rows x 64 channels (grid 256 x 2).
// Panels staged coalesced into LDS (summed agg 16 KB + X 16 KB); W halves
// copied from pre-transposed bf16 global (16+16 KB). Total LDS 64 KB,
// per-thread state ~50 VGPR -> no scratch spill (the R6 killer).
// ---------------------------------------------------------------------------
template<int S>
__global__ __launch_bounds__(256) void k2_gemm(
        const float* __restrict__ aggS, const float* __restrict__ deg,
        const float* __restrict__ X,
        const unsigned short* __restrict__ WtNg,
        const unsigned short* __restrict__ WtCg,
        const float* __restrict__ bn, const float* __restrict__ bc,
        float* __restrict__ h, float* __restrict__ bsum, float* __restrict__ bsq) {
    __shared__ __align__(16) float as[32 * 128];            // 16 KB summed agg
    __shared__ __align__(16) float xs[32 * 128];            // 16 KB X panel
    __shared__ __align__(16) unsigned short wn[128 * 64];   // 16 KB [k][c-half]
    __shared__ __align__(16) unsigned short wc[128 * 64];   // 16 KB
    const int tid = threadIdx.x;
    const int rb = blockIdx.x;         // row-block: 32 rows
    const int ch = blockIdx.y;         // c-half: 0..1
    const int i0 = rb * 32;

    // stage W half (pure coalesced copy, conflict-free sequential LDS writes)
    for (int idx = tid; idx < 1024; idx += 256) {
        int k = idx >> 3, u = (idx & 7) * 8;
        *reinterpret_cast<uint4*>(&wn[k * 64 + u]) =
            *reinterpret_cast<const uint4*>(&WtNg[k * 128 + ch * 64 + u]);
        *reinterpret_cast<uint4*>(&wc[k * 64 + u]) =
            *reinterpret_cast<const uint4*>(&WtCg[k * 128 + ch * 64 + u]);
    }
    // stage panels (coalesced float4, each byte read once)
    for (int idx = tid; idx < 1024; idx += 256) {
        size_t off = (size_t)i0 * CC + (size_t)idx * 4;
        float4 p = *reinterpret_cast<const float4*>(aggS + off);
        #pragma unroll
        for (int ss = 1; ss < S; ++ss) {
            float4 q = *reinterpret_cast<const float4*>(
                aggS + (size_t)ss * (NN * CC) + off);
            p.x += q.x; p.y += q.y; p.z += q.z; p.w += q.w;
        }
        *reinterpret_cast<float4*>(&as[idx * 4]) = p;
        *reinterpret_cast<float4*>(&xs[idx * 4]) =
            *reinterpret_cast<const float4*>(X + off);
    }
    __syncthreads();

    const int c  = tid & 63;
    const int rg = tid >> 6;           // 4 groups x 8 rows
    float accN[8], accC[8];
    #pragma unroll
    for (int r = 0; r < 8; ++r) { accN[r] = 0.0f; accC[r] = 0.0f; }

    for (int k = 0; k < 128; k += 4) {
        float wn4[4], wc4[4];
        #pragma unroll
        for (int kk = 0; kk < 4; ++kk) {
            wn4[kk] = bf2f(wn[(k + kk) * 64 + c]);   // lanes consecutive: free
            wc4[kk] = bf2f(wc[(k + kk) * 64 + c]);
        }
        #pragma unroll
        for (int r = 0; r < 8; ++r) {
            float4 av = *reinterpret_cast<const float4*>(&as[(rg * 8 + r) * 128 + k]);
            float4 xv = *reinterpret_cast<const float4*>(&xs[(rg * 8 + r) * 128 + k]);
            accN[r] = fmaf(av.x, wn4[0], accN[r]);
            accN[r] = fmaf(av.y, wn4[1], accN[r]);
            accN[r] = fmaf(av.z, wn4[2], accN[r]);
            accN[r] = fmaf(av.w, wn4[3], accN[r]);
            accC[r] = fmaf(xv.x, wc4[0], accC[r]);
            accC[r] = fmaf(xv.y, wc4[1], accC[r]);
            accC[r] = fmaf(xv.z, wc4[2], accC[r]);
            accC[r] = fmaf(xv.w, wc4[3], accC[r]);
        }
    }

    const int cg = ch * 64 + c;
    const float bnc = bn[cg], bcc = bc[cg];
    float sp = 0.0f, sq = 0.0f;
    #pragma unroll
    for (int r = 0; r < 8; ++r) {
        int row = i0 + rg * 8 + r;
        float d  = deg[row];
        float rd = (d == 0.0f) ? 1.0f : (1.0f / d);
        float hv = accN[r] * rd + accC[r] + bnc + bcc;
        h[(size_t)row * CC + cg] = hv;               // lanes: c consecutive
        sp += hv; sq += hv * hv;
    }
    __syncthreads();                                  // panel reads done
    float* red = as;
    red[rg * 64 + c]       = sp;
    red[256 + rg * 64 + c] = sq;
    __syncthreads();
    if (rg == 0) {
        atomicAdd(&bsum[cg], red[c] + red[64 + c] + red[128 + c] + red[192 + c]);
        atomicAdd(&bsq[cg],
                  red[256 + c] + red[320 + c] + red[384 + c] + red[448 + c]);
    }
}

// ---------------------------------------------------------------------------
// Kernel 3: out = relu(gamma * (h - mu) * rsqrt(var + eps) + beta), float4.
// ---------------------------------------------------------------------------
__global__ __launch_bounds__(256) void k4_bn(
        const float* __restrict__ h, const float* __restrict__ bsum,
        const float* __restrict__ bsq, const float* __restrict__ gamma,
        const float* __restrict__ beta, float* __restrict__ out) {
    const int idx = (blockIdx.x * 256 + threadIdx.x) * 4;
    const int c0  = idx & 127;
    float4 hv = *reinterpret_cast<const float4*>(h + idx);
    float4 s4 = *reinterpret_cast<const float4*>(bsum + c0);
    float4 q4 = *reinterpret_cast<const float4*>(bsq + c0);
    float4 g4 = *reinterpret_cast<const float4*>(gamma + c0);
    float4 b4 = *reinterpret_cast<const float4*>(beta + c0);
    const float invN = 1.0f / 8192.0f;
    float4 o;
    const float* hp = &hv.x; const float* sp = &s4.x; const float* qp = &q4.x;
    const float* gp = &g4.x; const float* bp = &b4.x; float* op = &o.x;
    #pragma unroll
    for (int jj = 0; jj < 4; ++jj) {
        float mu  = sp[jj] * invN;
        float var = qp[jj] * invN - mu * mu;
        float sc  = gp[jj] * rsqrtf(var + BN_EPS);
        float v   = (hp[jj] - mu) * sc + bp[jj];
        op[jj] = v > 0.0f ? v : 0.0f;
    }
    *reinterpret_cast<float4*>(out + idx) = o;
}

extern "C" void kernel_launch(void* const* d_in, const int* in_sizes, int n_in,
                              void* d_out, int out_size, void* d_ws, size_t ws_size,
                              hipStream_t stream) {
    const float* X     = (const float*)d_in[0];   // [8192,128]
    const float* A     = (const float*)d_in[1];   // [8192,8192]
    const float* Wn    = (const float*)d_in[2];   // [128,128]
    const float* bn    = (const float*)d_in[3];
    const float* Wc    = (const float*)d_in[4];
    const float* bc    = (const float*)d_in[5];
    const float* gamma = (const float*)d_in[6];
    const float* beta  = (const float*)d_in[7];
    float* out = (float*)d_out;

    const size_t sliceB = 4194304;                // 4 MB per slice
    const size_t smallB = 41984;                  // deg+bsum+bsq+cnt
    const size_t wB     = 65536;                  // 2 x 32 KB transposed bf16 W
    const int S = (ws_size >= 4 * sliceB + smallB + wB + sliceB) ? 4 : 2;

    char* ws = (char*)d_ws;
    float*          aggS  = (float*)(ws);                 // S x 4 MB, plain stores
    char*           smal  = ws + (size_t)S * sliceB;
    float*          deg   = (float*)(smal);               // 32 KB (memset 0)
    float*          bsum  = (float*)(smal + 32768);       // 512 B (memset 0)
    float*          bsq   = (float*)(smal + 33280);       // 512 B (memset 0)
    unsigned*       cnt   = (unsigned*)(smal + 33792);    // 8 KB  (memset 0)
    unsigned short* WtNg  = (unsigned short*)(smal + smallB);
    unsigned short* WtCg  = (unsigned short*)(smal + smallB + 32768);
    float*          h     = (float*)(smal + smallB + wB); // 4 MB
    unsigned*       edges = (unsigned*)(smal + smallB + wB); // aliases h

    hipMemsetAsync(smal, 0, smallB, stream);

    k0_prep<<<32, 256, 0, stream>>>(Wn, Wc, WtNg, WtCg);
    k1_scan<<<dim3(64, 32), 256, 0, stream>>>(A, deg, cnt, edges);
    if (S == 4)
        k1b_gather<512><<<dim3(64, 4), 512, 0, stream>>>(X, cnt, edges, aggS);
    else
        k1b_gather<1024><<<dim3(64, 2), 1024, 0, stream>>>(X, cnt, edges, aggS);
    if (S == 4)
        k2_gemm<4><<<dim3(256, 2), 256, 0, stream>>>(aggS, deg, X, WtNg, WtCg,
                                                     bn, bc, h, bsum, bsq);
    else
        k2_gemm<2><<<dim3(256, 2), 256, 0, stream>>>(aggS, deg, X, WtNg, WtCg,
                                                     bn, bc, h, bsum, bsq);
    k4_bn<<<1024, 256, 0, stream>>>(h, bsum, bsq, gamma, beta, out);
}